// Round 2
// baseline (1769.074 us; speedup 1.0000x reference)
//
#include <hip/hip_runtime.h>
#include <hip/hip_bf16.h>
#include <math.h>

// Problem constants (match reference)
#define N_NODES 100000
#define N_EDGES 3200000
#define HID 128
#define LAYERS 8
#define ALPHA 0.1f
#define THETA 0.5f

// Bucketed CSR build: 391 buckets x 256 dst nodes.
#define NBKT 391
#define BKT_STRIDE 10240
#define EPT 16
#define CHUNK 4096   // edges per block in k_bucket (256 thr x 16)

typedef unsigned int uint;
typedef unsigned short ushort;
typedef __attribute__((ext_vector_type(8))) short short8;   // 8 bf16 (4 VGPRs)
typedef __attribute__((ext_vector_type(4))) float f32x4;    // MFMA acc

// bf16 helpers: node features stored as packed bf16 pairs (uint = 2 cols)
__device__ inline float bf_lo(uint p) { return __uint_as_float(p << 16); }
__device__ inline float bf_hi(uint p) { return __uint_as_float(p & 0xffff0000u); }
__device__ inline uint bf_pack(float x, float y) {
    uint ux = __float_as_uint(x), uy = __float_as_uint(y);
    uint rx = (ux + 0x7fffu + ((ux >> 16) & 1u)) >> 16;
    uint ry = (uy + 0x7fffu + ((uy >> 16) & 1u)) >> 16;
    return rx | (ry << 16);
}
__device__ inline ushort bfr(float x) {
    uint u = __float_as_uint(x);
    return (ushort)((u + 0x7fffu + ((u >> 16) & 1u)) >> 16);
}
__device__ inline float bff(ushort s) { return __uint_as_float(((uint)s) << 16); }

// ---------------------------------------------------------------------------
// Pass A: chunk-wise counting sort of edges into 391 dst-buckets.
// ---------------------------------------------------------------------------
__global__ __launch_bounds__(256) void k_bucket(const int* __restrict__ rowi,
                                                const int* __restrict__ coli,
                                                uint* __restrict__ eb,
                                                int* __restrict__ gcnt) {
    __shared__ int bcnt[NBKT];
    __shared__ int gbase[NBKT];
    int t = threadIdx.x;
    for (int i = t; i < NBKT; i += 256) bcnt[i] = 0;
    __syncthreads();

    int e0 = blockIdx.x * CHUNK;
    int bk[EPT];
    int rk[EPT];
    uint rec[EPT];
#pragma unroll
    for (int j = 0; j < EPT; ++j) {
        int e = e0 + j * 256 + t;
        if (e < N_EDGES) {
            int r = rowi[e];
            int c = coli[e];
            bk[j] = c >> 8;
            rec[j] = ((uint)r << 8) | (uint)(c & 255);
            rk[j] = atomicAdd(&bcnt[bk[j]], 1);
        } else {
            bk[j] = -1;
        }
    }
    __syncthreads();
    for (int i = t; i < NBKT; i += 256) {
        int n = bcnt[i];
        gbase[i] = n ? atomicAdd(&gcnt[i], n) : 0;
    }
    __syncthreads();
#pragma unroll
    for (int j = 0; j < EPT; ++j) {
        if (bk[j] >= 0)
            eb[(size_t)bk[j] * BKT_STRIDE + gbase[bk[j]] + rk[j]] = rec[j];
    }
}

// Pass B: exclusive scan of the 391 bucket counts -> bucket bases in csr.
__global__ __launch_bounds__(512) void k_bscan(const int* __restrict__ gcnt,
                                               int* __restrict__ bbase) {
    __shared__ int lds[512];
    int t = threadIdx.x;
    int v = (t < NBKT) ? gcnt[t] : 0;
    lds[t] = v;
    __syncthreads();
    for (int off = 1; off < 512; off <<= 1) {
        int u = (t >= off) ? lds[t - off] : 0;
        __syncthreads();
        lds[t] += u;
        __syncthreads();
    }
    if (t < NBKT) bbase[t] = lds[t] - v;
}

// Pass C: per bucket, count edges per node in LDS, emit dinv + indptr.
__global__ __launch_bounds__(256) void k_node_ipt(const uint* __restrict__ eb,
                                                  const int* __restrict__ gcnt,
                                                  const int* __restrict__ bbase,
                                                  float* __restrict__ dinv,
                                                  int* __restrict__ indptr) {
    __shared__ int ncnt[256];
    __shared__ int sc[256];
    int b = blockIdx.x;
    int t = threadIdx.x;
    ncnt[t] = 0;
    __syncthreads();
    int ne = gcnt[b];
    const uint* ebp = eb + (size_t)b * BKT_STRIDE;
    for (int i = t; i < ne; i += 256) atomicAdd(&ncnt[ebp[i] & 255], 1);
    __syncthreads();
    int v = ncnt[t];
    sc[t] = v;
    __syncthreads();
    for (int off = 1; off < 256; off <<= 1) {
        int u = (t >= off) ? sc[t - off] : 0;
        __syncthreads();
        sc[t] += u;
        __syncthreads();
    }
    int node = b * 256 + t;
    if (node < N_NODES) {
        dinv[node] = rsqrtf((float)(v + 1));      // +1 self loop
        indptr[node] = bbase[b] + (sc[t] - v);
    }
    if (b == NBKT - 1 && t == 255) indptr[N_NODES] = N_EDGES;
}

// Pass D: per bucket, scatter final (r, norm) records into a single-CU window.
__global__ __launch_bounds__(256) void k_fill2(const uint* __restrict__ eb,
                                               const int* __restrict__ gcnt,
                                               const float* __restrict__ dinv,
                                               const int* __restrict__ indptr,
                                               int2* __restrict__ csr) {
    __shared__ float sdv[256];
    __shared__ int scur[256];
    __shared__ int sipt[256];
    int b = blockIdx.x;
    int t = threadIdx.x;
    int node = b * 256 + t;
    sdv[t] = (node < N_NODES) ? dinv[node] : 0.f;
    sipt[t] = (node < N_NODES) ? indptr[node] : 0;
    scur[t] = 0;
    __syncthreads();
    int ne = gcnt[b];
    const uint* ebp = eb + (size_t)b * BKT_STRIDE;
    for (int i = t; i < ne; i += 256) {
        uint rec = ebp[i];
        int lc = rec & 255;
        int r = (int)(rec >> 8);
        int pos = sipt[lc] + atomicAdd(&scur[lc], 1);
        csr[pos] = make_int2(r, __float_as_int(dinv[r] * sdv[lc]));
    }
}

// ---------------------------------------------------------------------------
// W_gcn prep: bf16 + transpose -> Wt[l][c][k]  (runs once per call, 8 blocks)
// ---------------------------------------------------------------------------
__global__ __launch_bounds__(256) void k_wprep(const float* __restrict__ Wg,
                                               ushort* __restrict__ Wt) {
    int l = blockIdx.x;
    const float* W = Wg + (size_t)l * HID * HID;
    ushort* T = Wt + (size_t)l * HID * HID;
    int t = threadIdx.x;
#pragma unroll
    for (int i = 0; i < 16; ++i) {
        int idx = t + 256 * i;          // float4 id, 0..4095
        int k = idx >> 5;               // 0..127
        int c4 = idx & 31;
        float4 v = *(const float4*)(W + (size_t)k * HID + c4 * 4);
        T[(c4 * 4 + 0) * HID + k] = bfr(v.x);
        T[(c4 * 4 + 1) * HID + k] = bfr(v.y);
        T[(c4 * 4 + 2) * HID + k] = bfr(v.z);
        T[(c4 * 4 + 3) * HID + k] = bfr(v.w);
    }
}

// ---------------------------------------------------------------------------
// GEMM initial projection: out0 = out1 = x@W_in + b_in  (fp32 in, bf16 out x2)
// ---------------------------------------------------------------------------
__global__ __launch_bounds__(256) void k_gemm_in(const float* __restrict__ A,
                                                 const float* __restrict__ W,
                                                 const float* __restrict__ bias,
                                                 uint* __restrict__ out0,
                                                 uint* __restrict__ out1) {
    __shared__ float sT[32 * 64];    // [k][r]
    __shared__ float Ws[32 * 128];   // [k][c]
    int t = threadIdx.x;
    int tr = t & 15;
    int tc = t >> 4;
    int rowBase = blockIdx.x * 64;
    float acc[4][8] = {};

    for (int ko = 0; ko < HID; ko += 32) {
#pragma unroll
        for (int pass = 0; pass < 2; ++pass) {
            int lin = t + 256 * pass;
            int r = lin >> 3;
            int kq = lin & 7;
            int ar = rowBase + r;
            if (ar >= N_NODES) ar = N_NODES - 1;
            float4 v = *(const float4*)(A + (size_t)ar * HID + ko + 4 * kq);
            sT[(4 * kq + 0) * 64 + r] = v.x;
            sT[(4 * kq + 1) * 64 + r] = v.y;
            sT[(4 * kq + 2) * 64 + r] = v.z;
            sT[(4 * kq + 3) * 64 + r] = v.w;
        }
#pragma unroll
        for (int pass = 0; pass < 4; ++pass) {
            int lin = t + 256 * pass;
            int k = lin >> 5;
            int c4 = lin & 31;
            *(float4*)&Ws[k * 128 + 4 * c4] =
                *(const float4*)(W + (size_t)(ko + k) * HID + 4 * c4);
        }
        __syncthreads();
#pragma unroll
        for (int k = 0; k < 32; ++k) {
            float4 a = *(const float4*)&sT[k * 64 + 4 * tr];
            float4 w0 = *(const float4*)&Ws[k * 128 + 8 * tc];
            float4 w1 = *(const float4*)&Ws[k * 128 + 8 * tc + 4];
            float av[4] = {a.x, a.y, a.z, a.w};
            float wv[8] = {w0.x, w0.y, w0.z, w0.w, w1.x, w1.y, w1.z, w1.w};
#pragma unroll
            for (int i = 0; i < 4; ++i)
#pragma unroll
                for (int j = 0; j < 8; ++j)
                    acc[i][j] = fmaf(av[i], wv[j], acc[i][j]);
        }
        __syncthreads();
    }

    int c0 = 8 * tc;
    float bb[8];
#pragma unroll
    for (int j = 0; j < 8; ++j) bb[j] = bias[c0 + j];
#pragma unroll
    for (int i = 0; i < 4; ++i) {
        int r = rowBase + 4 * tr + i;
        if (r >= N_NODES) break;
        float v[8];
#pragma unroll
        for (int j = 0; j < 8; ++j) v[j] = acc[i][j] + bb[j];
        uint4 o;
        o.x = bf_pack(v[0], v[1]);
        o.y = bf_pack(v[2], v[3]);
        o.z = bf_pack(v[4], v[5]);
        o.w = bf_pack(v[6], v[7]);
        *(uint4*)(out0 + (size_t)r * 64 + c0 / 2) = o;
        *(uint4*)(out1 + (size_t)r * 64 + c0 / 2) = o;
    }
}

// ---------------------------------------------------------------------------
// FUSED GCNII layer: per 64-row block,
//   phase 1 (spmm): wave wv computes s rows [16wv,16wv+16) straight into LDS
//     s[n] = 0.9*(sum_e nrm_e*h[src_e] + dinv^2*h[n]) + 0.1*h0[n]
//   phase 2 (MFMA): out = relu((1-beta)*s + beta*(s@W)), B-frags from global Wt
// Eliminates the 25.6MB s round-trip per layer; MFMA waves overlap gather
// latency of other blocks on the same CU. LDS 33KB -> 4 blocks/CU.
// ---------------------------------------------------------------------------
#define SAS 136   // ushort stride (128+8): 272B rows, 16B-aligned, bank-even

__global__ __launch_bounds__(256) void k_layer(const uint* __restrict__ h,
                                               const uint* __restrict__ h0,
                                               const float* __restrict__ dinv,
                                               const int* __restrict__ indptr,
                                               const int2* __restrict__ csr,
                                               const ushort* __restrict__ Wt,
                                               uint* __restrict__ out0,
                                               float beta) {
    __shared__ ushort sA[64 * SAS];
    __shared__ ushort pack[64 * 128];
    int t = threadIdx.x;
    int lane = t & 63;
    int wv = t >> 6;
    int rowBase = blockIdx.x * 64;

    // ---------------- phase 1: spmm into sA ----------------
#pragma unroll 1
    for (int i = 0; i < 16; ++i) {
        int r = wv * 16 + i;
        int node = rowBase + r;
        uint outv = 0;
        if (node < N_NODES) {
            int beg = indptr[node];
            int end = indptr[node + 1];
            float di = dinv[node];
            uint hs = h[node * 64 + lane];
            uint h0v = h0[node * 64 + lane];
            float ax[8], ay[8];
#pragma unroll
            for (int j = 0; j < 8; ++j) { ax[j] = 0.f; ay[j] = 0.f; }
            int e = beg;
            for (; e + 16 <= end; e += 16) {
                int2 rr[16];
#pragma unroll
                for (int j = 0; j < 16; ++j) rr[j] = csr[e + j];
                uint p[16];
#pragma unroll
                for (int j = 0; j < 16; ++j) p[j] = h[rr[j].x * 64 + lane];
#pragma unroll
                for (int j = 0; j < 16; ++j) {
                    float w = __int_as_float(rr[j].y);
                    ax[j & 7] = fmaf(w, bf_lo(p[j]), ax[j & 7]);
                    ay[j & 7] = fmaf(w, bf_hi(p[j]), ay[j & 7]);
                }
            }
            for (; e < end; e += 4) {
                int2 rr[4];
                float w[4];
#pragma unroll
                for (int j = 0; j < 4; ++j) {
                    int idx = e + j;
                    rr[j] = csr[idx < end ? idx : beg];
                    w[j] = (idx < end) ? __int_as_float(rr[j].y) : 0.f;
                }
                uint p[4];
#pragma unroll
                for (int j = 0; j < 4; ++j) p[j] = h[rr[j].x * 64 + lane];
#pragma unroll
                for (int j = 0; j < 4; ++j) {
                    ax[j] = fmaf(w[j], bf_lo(p[j]), ax[j]);
                    ay[j] = fmaf(w[j], bf_hi(p[j]), ay[j]);
                }
            }
            float sum0 = ((ax[0] + ax[1]) + (ax[2] + ax[3])) + ((ax[4] + ax[5]) + (ax[6] + ax[7]));
            float sum1 = ((ay[0] + ay[1]) + (ay[2] + ay[3])) + ((ay[4] + ay[5]) + (ay[6] + ay[7]));
            float selfw = di * di;
            float rx = (1.0f - ALPHA) * fmaf(selfw, bf_lo(hs), sum0) + ALPHA * bf_lo(h0v);
            float ry = (1.0f - ALPHA) * fmaf(selfw, bf_hi(hs), sum1) + ALPHA * bf_hi(h0v);
            outv = bf_pack(rx, ry);
        }
        ((uint*)(sA + r * SAS))[lane] = outv;
    }
    __syncthreads();

    // ---------------- phase 2: MFMA + epilogue ----------------
    int fr = lane & 15;
    int fq = lane >> 4;
    f32x4 acc[4][2] = {};
#pragma unroll
    for (int kc = 0; kc < 4; ++kc) {
        int kof = kc * 32 + fq * 8;
        short8 b0 = *(const short8*)(Wt + (size_t)(wv * 32 + fr) * HID + kof);
        short8 b1 = *(const short8*)(Wt + (size_t)(wv * 32 + 16 + fr) * HID + kof);
#pragma unroll
        for (int tm = 0; tm < 4; ++tm) {
            short8 a = *(const short8*)(sA + (tm * 16 + fr) * SAS + kof);
            acc[tm][0] = __builtin_amdgcn_mfma_f32_16x16x32_bf16(a, b0, acc[tm][0], 0, 0, 0);
            acc[tm][1] = __builtin_amdgcn_mfma_f32_16x16x32_bf16(a, b1, acc[tm][1], 0, 0, 0);
        }
    }

    float ob = 1.0f - beta;
#pragma unroll
    for (int tm = 0; tm < 4; ++tm)
#pragma unroll
        for (int tn = 0; tn < 2; ++tn)
#pragma unroll
            for (int r = 0; r < 4; ++r) {
                int row = tm * 16 + fq * 4 + r;
                int col = wv * 32 + tn * 16 + fr;
                float sv = bff(sA[row * SAS + col]);
                float val = fmaxf(fmaf(ob, sv, beta * acc[tm][tn][r]), 0.f);
                pack[row * 128 + col] = bfr(val);
            }
    __syncthreads();
#pragma unroll
    for (int i = 0; i < 4; ++i) {
        int idx = t + 256 * i;
        int r = idx >> 4;
        int q = idx & 15;
        int ar = rowBase + r;
        if (ar < N_NODES)
            *(uint4*)(out0 + (size_t)ar * 64 + q * 4) =
                *(const uint4*)((const uint*)(pack + r * 128) + q * 4);
    }
}

// ---------------------------------------------------------------------------
// Output: out[n] = dot(h[n], W_out) + b_out   (wave per node, bf16 h)
// ---------------------------------------------------------------------------
__global__ __launch_bounds__(256) void k_out(const uint* __restrict__ h,
                                             const float* __restrict__ W_out,
                                             const float* __restrict__ b_out,
                                             float* __restrict__ out) {
    int node = blockIdx.x * 4 + (threadIdx.x >> 6);
    if (node >= N_NODES) return;
    int lane = threadIdx.x & 63;
    uint p = h[node * 64 + lane];
    float2 wv = *(const float2*)(W_out + lane * 2);
    float pr = bf_lo(p) * wv.x + bf_hi(p) * wv.y;
#pragma unroll
    for (int off = 32; off > 0; off >>= 1) pr += __shfl_down(pr, off);
    if (lane == 0) out[node] = pr + b_out[0];
}

// ---------------------------------------------------------------------------
extern "C" void kernel_launch(void* const* d_in, const int* in_sizes, int n_in,
                              void* d_out, int out_size, void* d_ws, size_t ws_size,
                              hipStream_t stream) {
    const float* x     = (const float*)d_in[0];
    // d_in[1] edge_weight: unused by reference forward path
    const float* W_in  = (const float*)d_in[2];
    const float* b_in  = (const float*)d_in[3];
    const float* W_gcn = (const float*)d_in[4];
    const float* W_out = (const float*)d_in[5];
    const float* b_out = (const float*)d_in[6];
    const int*   ei    = (const int*)d_in[7];
    const int* rowi = ei;
    const int* coli = ei + N_EDGES;
    float* out = (float*)d_out;

    char* ws = (char*)d_ws;
    auto alloc = [&](size_t bytes) -> char* {
        char* p = ws;
        ws += (bytes + 255) & ~(size_t)255;
        return p;
    };
    float*  dinv    = (float*) alloc((size_t)N_NODES * 4);
    int*    indptr  = (int*)   alloc((size_t)(N_NODES + 1) * 4);
    int*    gcnt    = (int*)   alloc(2048 * 4);
    int*    bbase   = (int*)   alloc(2048 * 4);
    int2*   csr     = (int2*)  alloc((size_t)N_EDGES * 8);
    ushort* Wt      = (ushort*)alloc((size_t)LAYERS * HID * HID * 2);
    uint*   hA      = (uint*)  alloc((size_t)N_NODES * 64 * 4);  // bf16 x2 packed
    uint*   hB      = (uint*)  alloc((size_t)N_NODES * 64 * 4);
    uint*   h0      = (uint*)  alloc((size_t)N_NODES * 64 * 4);
    // bucket-sorted edge records (16.0 MB) alias hB: dead before first k_layer
    uint*   eb      = hB;

    hipMemsetAsync(gcnt, 0, (size_t)NBKT * 4, stream);

    k_bucket<<<(N_EDGES + CHUNK - 1) / CHUNK, 256, 0, stream>>>(rowi, coli, eb, gcnt);
    k_bscan<<<1, 512, 0, stream>>>(gcnt, bbase);
    k_node_ipt<<<NBKT, 256, 0, stream>>>(eb, gcnt, bbase, dinv, indptr);
    k_fill2<<<NBKT, 256, 0, stream>>>(eb, gcnt, dinv, indptr, csr);
    k_wprep<<<LAYERS, 256, 0, stream>>>(W_gcn, Wt);

    int gemm_blocks = (N_NODES + 63) / 64;
    // h0 = hA = x@W_in + b_in
    k_gemm_in<<<gemm_blocks, 256, 0, stream>>>(x, W_in, b_in, h0, hA);

    uint* hin = hA;
    uint* hout = hB;
    for (int l = 0; l < LAYERS; ++l) {
        float beta = logf(THETA / (float)(l + 1) + 1.0f);
        k_layer<<<gemm_blocks, 256, 0, stream>>>(hin, h0, dinv, indptr, csr,
                                                 Wt + (size_t)l * HID * HID,
                                                 hout, beta);
        uint* tmp = hin; hin = hout; hout = tmp;
    }
    k_out<<<(N_NODES + 3) / 4, 256, 0, stream>>>(hin, W_out, b_out, out);
}

// Round 3
// 1352.434 us; speedup vs baseline: 1.3081x; 1.3081x over previous
//
#include <hip/hip_runtime.h>
#include <hip/hip_bf16.h>
#include <math.h>

// Problem constants (match reference)
#define N_NODES 100000
#define N_EDGES 3200000
#define HID 128
#define LAYERS 8
#define ALPHA 0.1f
#define THETA 0.5f

// Bucketed CSR build: 391 buckets x 256 dst nodes.
#define NBKT 391
#define BKT_STRIDE 10240
#define EPT 16
#define CHUNK 4096   // edges per block in k_bucket (256 thr x 16)

typedef unsigned int uint;
typedef unsigned short ushort;
typedef __attribute__((ext_vector_type(8))) short short8;   // 8 bf16 (4 VGPRs)
typedef __attribute__((ext_vector_type(4))) float f32x4;    // MFMA acc

// bf16 helpers: node features stored as packed bf16 pairs (uint = 2 cols)
__device__ inline float bf_lo(uint p) { return __uint_as_float(p << 16); }
__device__ inline float bf_hi(uint p) { return __uint_as_float(p & 0xffff0000u); }
__device__ inline uint bf_pack(float x, float y) {
    uint ux = __float_as_uint(x), uy = __float_as_uint(y);
    uint rx = (ux + 0x7fffu + ((ux >> 16) & 1u)) >> 16;
    uint ry = (uy + 0x7fffu + ((uy >> 16) & 1u)) >> 16;
    return rx | (ry << 16);
}
__device__ inline ushort bfr(float x) {
    uint u = __float_as_uint(x);
    return (ushort)((u + 0x7fffu + ((u >> 16) & 1u)) >> 16);
}
__device__ inline float bff(ushort s) { return __uint_as_float(((uint)s) << 16); }

// ---------------------------------------------------------------------------
// Pass A: chunk-wise counting sort of edges into 391 dst-buckets.
// ---------------------------------------------------------------------------
__global__ __launch_bounds__(256) void k_bucket(const int* __restrict__ rowi,
                                                const int* __restrict__ coli,
                                                uint* __restrict__ eb,
                                                int* __restrict__ gcnt) {
    __shared__ int bcnt[NBKT];
    __shared__ int gbase[NBKT];
    int t = threadIdx.x;
    for (int i = t; i < NBKT; i += 256) bcnt[i] = 0;
    __syncthreads();

    int e0 = blockIdx.x * CHUNK;
    int bk[EPT];
    int rk[EPT];
    uint rec[EPT];
#pragma unroll
    for (int j = 0; j < EPT; ++j) {
        int e = e0 + j * 256 + t;
        if (e < N_EDGES) {
            int r = rowi[e];
            int c = coli[e];
            bk[j] = c >> 8;
            rec[j] = ((uint)r << 8) | (uint)(c & 255);
            rk[j] = atomicAdd(&bcnt[bk[j]], 1);
        } else {
            bk[j] = -1;
        }
    }
    __syncthreads();
    for (int i = t; i < NBKT; i += 256) {
        int n = bcnt[i];
        gbase[i] = n ? atomicAdd(&gcnt[i], n) : 0;
    }
    __syncthreads();
#pragma unroll
    for (int j = 0; j < EPT; ++j) {
        if (bk[j] >= 0)
            eb[(size_t)bk[j] * BKT_STRIDE + gbase[bk[j]] + rk[j]] = rec[j];
    }
}

// Pass B: exclusive scan of the 391 bucket counts -> bucket bases in csr.
__global__ __launch_bounds__(512) void k_bscan(const int* __restrict__ gcnt,
                                               int* __restrict__ bbase) {
    __shared__ int lds[512];
    int t = threadIdx.x;
    int v = (t < NBKT) ? gcnt[t] : 0;
    lds[t] = v;
    __syncthreads();
    for (int off = 1; off < 512; off <<= 1) {
        int u = (t >= off) ? lds[t - off] : 0;
        __syncthreads();
        lds[t] += u;
        __syncthreads();
    }
    if (t < NBKT) bbase[t] = lds[t] - v;
}

// Pass C: per bucket, count edges per node in LDS, emit dinv + indptr.
__global__ __launch_bounds__(256) void k_node_ipt(const uint* __restrict__ eb,
                                                  const int* __restrict__ gcnt,
                                                  const int* __restrict__ bbase,
                                                  float* __restrict__ dinv,
                                                  int* __restrict__ indptr) {
    __shared__ int ncnt[256];
    __shared__ int sc[256];
    int b = blockIdx.x;
    int t = threadIdx.x;
    ncnt[t] = 0;
    __syncthreads();
    int ne = gcnt[b];
    const uint* ebp = eb + (size_t)b * BKT_STRIDE;
    for (int i = t; i < ne; i += 256) atomicAdd(&ncnt[ebp[i] & 255], 1);
    __syncthreads();
    int v = ncnt[t];
    sc[t] = v;
    __syncthreads();
    for (int off = 1; off < 256; off <<= 1) {
        int u = (t >= off) ? sc[t - off] : 0;
        __syncthreads();
        sc[t] += u;
        __syncthreads();
    }
    int node = b * 256 + t;
    if (node < N_NODES) {
        dinv[node] = rsqrtf((float)(v + 1));      // +1 self loop
        indptr[node] = bbase[b] + (sc[t] - v);
    }
    if (b == NBKT - 1 && t == 255) indptr[N_NODES] = N_EDGES;
}

// Pass D: per bucket, scatter final (r, norm) records into a single-CU window.
__global__ __launch_bounds__(256) void k_fill2(const uint* __restrict__ eb,
                                               const int* __restrict__ gcnt,
                                               const float* __restrict__ dinv,
                                               const int* __restrict__ indptr,
                                               int2* __restrict__ csr) {
    __shared__ float sdv[256];
    __shared__ int scur[256];
    __shared__ int sipt[256];
    int b = blockIdx.x;
    int t = threadIdx.x;
    int node = b * 256 + t;
    sdv[t] = (node < N_NODES) ? dinv[node] : 0.f;
    sipt[t] = (node < N_NODES) ? indptr[node] : 0;
    scur[t] = 0;
    __syncthreads();
    int ne = gcnt[b];
    const uint* ebp = eb + (size_t)b * BKT_STRIDE;
    for (int i = t; i < ne; i += 256) {
        uint rec = ebp[i];
        int lc = rec & 255;
        int r = (int)(rec >> 8);
        int pos = sipt[lc] + atomicAdd(&scur[lc], 1);
        csr[pos] = make_int2(r, __float_as_int(dinv[r] * sdv[lc]));
    }
}

// ---------------------------------------------------------------------------
// W_gcn prep: bf16 + transpose -> Wt[l][c][k]  (runs once per call, 8 blocks)
// ---------------------------------------------------------------------------
__global__ __launch_bounds__(256) void k_wprep(const float* __restrict__ Wg,
                                               ushort* __restrict__ Wt) {
    int l = blockIdx.x;
    const float* W = Wg + (size_t)l * HID * HID;
    ushort* T = Wt + (size_t)l * HID * HID;
    int t = threadIdx.x;
#pragma unroll
    for (int i = 0; i < 16; ++i) {
        int idx = t + 256 * i;          // float4 id, 0..4095
        int k = idx >> 5;               // 0..127
        int c4 = idx & 31;
        float4 v = *(const float4*)(W + (size_t)k * HID + c4 * 4);
        T[(c4 * 4 + 0) * HID + k] = bfr(v.x);
        T[(c4 * 4 + 1) * HID + k] = bfr(v.y);
        T[(c4 * 4 + 2) * HID + k] = bfr(v.z);
        T[(c4 * 4 + 3) * HID + k] = bfr(v.w);
    }
}

// ---------------------------------------------------------------------------
// SpMM (bf16 features): s[n] = 0.9*(sum_e nrm_e*h[src_e] + dinv^2*h[n]) + 0.1*h0[n]
// 32 lanes per node, 2 nodes per wave; lane holds 4 features (2 packed uints,
// 8B dwordx2 gathers). ~30% fewer VALU instr/edge than the 64-lane version
// and 2x the bytes in flight per load. Divergence cost: trip = max(degA,degB)
// across the two wave halves (~9% masked-lane waste for Poisson(32) degrees).
// ---------------------------------------------------------------------------
__global__ __launch_bounds__(256) void k_spmm(const uint* __restrict__ h,
                                              const uint* __restrict__ h0,
                                              const float* __restrict__ dinv,
                                              const int* __restrict__ indptr,
                                              const int2* __restrict__ csr,
                                              uint* __restrict__ s_out) {
    int node = blockIdx.x * 8 + (threadIdx.x >> 5);
    if (node >= N_NODES) return;
    int l = threadIdx.x & 31;
    int beg = indptr[node];
    int end = indptr[node + 1];
    // prefetch self/residual rows early (independent of edge loop)
    float di = dinv[node];
    uint2 hs = *(const uint2*)(h + node * 64 + l * 2);
    uint2 h0v = *(const uint2*)(h0 + node * 64 + l * 2);
    float a0[2] = {0.f, 0.f}, a1[2] = {0.f, 0.f};
    float a2[2] = {0.f, 0.f}, a3[2] = {0.f, 0.f};
    int e = beg;
    for (; e + 8 <= end; e += 8) {
        int2 rr[8];
#pragma unroll
        for (int j = 0; j < 8; ++j) rr[j] = csr[e + j];
        uint2 p[8];
#pragma unroll
        for (int j = 0; j < 8; ++j) p[j] = *(const uint2*)(h + rr[j].x * 64 + l * 2);
#pragma unroll
        for (int j = 0; j < 8; ++j) {
            float w = __int_as_float(rr[j].y);
            int d = j & 1;
            a0[d] = fmaf(w, bf_lo(p[j].x), a0[d]);
            a1[d] = fmaf(w, bf_hi(p[j].x), a1[d]);
            a2[d] = fmaf(w, bf_lo(p[j].y), a2[d]);
            a3[d] = fmaf(w, bf_hi(p[j].y), a3[d]);
        }
    }
    for (; e < end; e += 2) {
        int2 rr[2];
        float w[2];
#pragma unroll
        for (int j = 0; j < 2; ++j) {
            int idx = e + j;
            rr[j] = csr[idx < end ? idx : beg];
            w[j] = (idx < end) ? __int_as_float(rr[j].y) : 0.f;
        }
        uint2 p[2];
#pragma unroll
        for (int j = 0; j < 2; ++j) p[j] = *(const uint2*)(h + rr[j].x * 64 + l * 2);
#pragma unroll
        for (int j = 0; j < 2; ++j) {
            a0[j] = fmaf(w[j], bf_lo(p[j].x), a0[j]);
            a1[j] = fmaf(w[j], bf_hi(p[j].x), a1[j]);
            a2[j] = fmaf(w[j], bf_lo(p[j].y), a2[j]);
            a3[j] = fmaf(w[j], bf_hi(p[j].y), a3[j]);
        }
    }
    float s0 = a0[0] + a0[1];
    float s1 = a1[0] + a1[1];
    float s2 = a2[0] + a2[1];
    float s3 = a3[0] + a3[1];
    float selfw = di * di;
    float rx = (1.0f - ALPHA) * fmaf(selfw, bf_lo(hs.x), s0) + ALPHA * bf_lo(h0v.x);
    float ry = (1.0f - ALPHA) * fmaf(selfw, bf_hi(hs.x), s1) + ALPHA * bf_hi(h0v.x);
    float rz = (1.0f - ALPHA) * fmaf(selfw, bf_lo(hs.y), s2) + ALPHA * bf_lo(h0v.y);
    float rw = (1.0f - ALPHA) * fmaf(selfw, bf_hi(hs.y), s3) + ALPHA * bf_hi(h0v.y);
    uint2 o;
    o.x = bf_pack(rx, ry);
    o.y = bf_pack(rz, rw);
    *(uint2*)(s_out + node * 64 + l * 2) = o;
}

// ---------------------------------------------------------------------------
// GEMM initial projection: out0 = out1 = x@W_in + b_in  (fp32 in, bf16 out x2)
// ---------------------------------------------------------------------------
__global__ __launch_bounds__(256) void k_gemm_in(const float* __restrict__ A,
                                                 const float* __restrict__ W,
                                                 const float* __restrict__ bias,
                                                 uint* __restrict__ out0,
                                                 uint* __restrict__ out1) {
    __shared__ float sT[32 * 64];    // [k][r]
    __shared__ float Ws[32 * 128];   // [k][c]
    int t = threadIdx.x;
    int tr = t & 15;
    int tc = t >> 4;
    int rowBase = blockIdx.x * 64;
    float acc[4][8] = {};

    for (int ko = 0; ko < HID; ko += 32) {
#pragma unroll
        for (int pass = 0; pass < 2; ++pass) {
            int lin = t + 256 * pass;
            int r = lin >> 3;
            int kq = lin & 7;
            int ar = rowBase + r;
            if (ar >= N_NODES) ar = N_NODES - 1;
            float4 v = *(const float4*)(A + (size_t)ar * HID + ko + 4 * kq);
            sT[(4 * kq + 0) * 64 + r] = v.x;
            sT[(4 * kq + 1) * 64 + r] = v.y;
            sT[(4 * kq + 2) * 64 + r] = v.z;
            sT[(4 * kq + 3) * 64 + r] = v.w;
        }
#pragma unroll
        for (int pass = 0; pass < 4; ++pass) {
            int lin = t + 256 * pass;
            int k = lin >> 5;
            int c4 = lin & 31;
            *(float4*)&Ws[k * 128 + 4 * c4] =
                *(const float4*)(W + (size_t)(ko + k) * HID + 4 * c4);
        }
        __syncthreads();
#pragma unroll
        for (int k = 0; k < 32; ++k) {
            float4 a = *(const float4*)&sT[k * 64 + 4 * tr];
            float4 w0 = *(const float4*)&Ws[k * 128 + 8 * tc];
            float4 w1 = *(const float4*)&Ws[k * 128 + 8 * tc + 4];
            float av[4] = {a.x, a.y, a.z, a.w};
            float wv[8] = {w0.x, w0.y, w0.z, w0.w, w1.x, w1.y, w1.z, w1.w};
#pragma unroll
            for (int i = 0; i < 4; ++i)
#pragma unroll
                for (int j = 0; j < 8; ++j)
                    acc[i][j] = fmaf(av[i], wv[j], acc[i][j]);
        }
        __syncthreads();
    }

    int c0 = 8 * tc;
    float bb[8];
#pragma unroll
    for (int j = 0; j < 8; ++j) bb[j] = bias[c0 + j];
#pragma unroll
    for (int i = 0; i < 4; ++i) {
        int r = rowBase + 4 * tr + i;
        if (r >= N_NODES) break;
        float v[8];
#pragma unroll
        for (int j = 0; j < 8; ++j) v[j] = acc[i][j] + bb[j];
        uint4 o;
        o.x = bf_pack(v[0], v[1]);
        o.y = bf_pack(v[2], v[3]);
        o.z = bf_pack(v[4], v[5]);
        o.w = bf_pack(v[6], v[7]);
        *(uint4*)(out0 + (size_t)r * 64 + c0 / 2) = o;
        *(uint4*)(out1 + (size_t)r * 64 + c0 / 2) = o;
    }
}

// ---------------------------------------------------------------------------
// GCNII layer GEMM (MFMA bf16): out = relu((1-beta)*s + beta*(s@W))
// 64 rows x 128 cols per block, 4 waves; wave w owns cols [32w, 32w+32).
// B-fragments read directly from global Wt (32KB/layer, L1/L2-hot broadcast):
// no sW staging -> LDS 52KB -> 33.8KB (3 -> 4 blocks/CU), one less barrier.
// ---------------------------------------------------------------------------
#define SAS 136   // ushort stride (128+8): 272B rows, 16B-aligned, bank-even

__global__ __launch_bounds__(256) void k_gemm_layer(const uint* __restrict__ A,
                                                    const ushort* __restrict__ Wt,
                                                    uint* __restrict__ out0,
                                                    float beta) {
    __shared__ ushort sA[64 * SAS];
    __shared__ ushort pack[64 * 128];
    int t = threadIdx.x;
    int lane = t & 63;
    int wv = t >> 6;
    int rowBase = blockIdx.x * 64;

#pragma unroll
    for (int i = 0; i < 4; ++i) {
        int idx = t + 256 * i;          // 0..1023
        int r = idx >> 4;               // 0..63
        int q = idx & 15;               // uint4 within row
        int ar = rowBase + r;
        if (ar >= N_NODES) ar = N_NODES - 1;
        uint4 v = *(const uint4*)(A + (size_t)ar * 64 + q * 4);
        *(uint4*)((uint*)(sA + r * SAS) + q * 4) = v;
    }
    __syncthreads();

    int fr = lane & 15;
    int fq = lane >> 4;
    const ushort* Wb0 = Wt + (size_t)(wv * 32 + fr) * HID;
    const ushort* Wb1 = Wt + (size_t)(wv * 32 + 16 + fr) * HID;
    f32x4 acc[4][2] = {};
#pragma unroll
    for (int kc = 0; kc < 4; ++kc) {
        int kof = kc * 32 + fq * 8;
        short8 b0 = *(const short8*)(Wb0 + kof);
        short8 b1 = *(const short8*)(Wb1 + kof);
#pragma unroll
        for (int tm = 0; tm < 4; ++tm) {
            short8 a = *(const short8*)(sA + (tm * 16 + fr) * SAS + kof);
            acc[tm][0] = __builtin_amdgcn_mfma_f32_16x16x32_bf16(a, b0, acc[tm][0], 0, 0, 0);
            acc[tm][1] = __builtin_amdgcn_mfma_f32_16x16x32_bf16(a, b1, acc[tm][1], 0, 0, 0);
        }
    }

    float ob = 1.0f - beta;
#pragma unroll
    for (int tm = 0; tm < 4; ++tm)
#pragma unroll
        for (int tn = 0; tn < 2; ++tn)
#pragma unroll
            for (int r = 0; r < 4; ++r) {
                int row = tm * 16 + fq * 4 + r;
                int col = wv * 32 + tn * 16 + fr;
                float sv = bff(sA[row * SAS + col]);
                float val = fmaxf(fmaf(ob, sv, beta * acc[tm][tn][r]), 0.f);
                pack[row * 128 + col] = bfr(val);
            }
    __syncthreads();
#pragma unroll
    for (int i = 0; i < 4; ++i) {
        int idx = t + 256 * i;
        int r = idx >> 4;
        int q = idx & 15;
        int ar = rowBase + r;
        if (ar < N_NODES)
            *(uint4*)(out0 + (size_t)ar * 64 + q * 4) =
                *(const uint4*)((const uint*)(pack + r * 128) + q * 4);
    }
}

// ---------------------------------------------------------------------------
// Output: out[n] = dot(h[n], W_out) + b_out   (wave per node, bf16 h)
// ---------------------------------------------------------------------------
__global__ __launch_bounds__(256) void k_out(const uint* __restrict__ h,
                                             const float* __restrict__ W_out,
                                             const float* __restrict__ b_out,
                                             float* __restrict__ out) {
    int node = blockIdx.x * 4 + (threadIdx.x >> 6);
    if (node >= N_NODES) return;
    int lane = threadIdx.x & 63;
    uint p = h[node * 64 + lane];
    float2 wv = *(const float2*)(W_out + lane * 2);
    float pr = bf_lo(p) * wv.x + bf_hi(p) * wv.y;
#pragma unroll
    for (int off = 32; off > 0; off >>= 1) pr += __shfl_down(pr, off);
    if (lane == 0) out[node] = pr + b_out[0];
}

// ---------------------------------------------------------------------------
extern "C" void kernel_launch(void* const* d_in, const int* in_sizes, int n_in,
                              void* d_out, int out_size, void* d_ws, size_t ws_size,
                              hipStream_t stream) {
    const float* x     = (const float*)d_in[0];
    // d_in[1] edge_weight: unused by reference forward path
    const float* W_in  = (const float*)d_in[2];
    const float* b_in  = (const float*)d_in[3];
    const float* W_gcn = (const float*)d_in[4];
    const float* W_out = (const float*)d_in[5];
    const float* b_out = (const float*)d_in[6];
    const int*   ei    = (const int*)d_in[7];
    const int* rowi = ei;
    const int* coli = ei + N_EDGES;
    float* out = (float*)d_out;

    char* ws = (char*)d_ws;
    auto alloc = [&](size_t bytes) -> char* {
        char* p = ws;
        ws += (bytes + 255) & ~(size_t)255;
        return p;
    };
    float*  dinv    = (float*) alloc((size_t)N_NODES * 4);
    int*    indptr  = (int*)   alloc((size_t)(N_NODES + 1) * 4);
    int*    gcnt    = (int*)   alloc(2048 * 4);
    int*    bbase   = (int*)   alloc(2048 * 4);
    int2*   csr     = (int2*)  alloc((size_t)N_EDGES * 8);
    ushort* Wt      = (ushort*)alloc((size_t)LAYERS * HID * HID * 2);
    uint*   hA      = (uint*)  alloc((size_t)N_NODES * 64 * 4);  // bf16 x2 packed
    uint*   hB      = (uint*)  alloc((size_t)N_NODES * 64 * 4);
    uint*   h0      = (uint*)  alloc((size_t)N_NODES * 64 * 4);
    // bucket-sorted edge records (16.0 MB) alias hB: dead before first k_spmm
    uint*   eb      = hB;

    hipMemsetAsync(gcnt, 0, (size_t)NBKT * 4, stream);

    k_bucket<<<(N_EDGES + CHUNK - 1) / CHUNK, 256, 0, stream>>>(rowi, coli, eb, gcnt);
    k_bscan<<<1, 512, 0, stream>>>(gcnt, bbase);
    k_node_ipt<<<NBKT, 256, 0, stream>>>(eb, gcnt, bbase, dinv, indptr);
    k_fill2<<<NBKT, 256, 0, stream>>>(eb, gcnt, dinv, indptr, csr);
    k_wprep<<<LAYERS, 256, 0, stream>>>(W_gcn, Wt);

    int gemm_blocks = (N_NODES + 63) / 64;
    // h0 = hA = x@W_in + b_in
    k_gemm_in<<<gemm_blocks, 256, 0, stream>>>(x, W_in, b_in, h0, hA);

    uint* hin = hA;
    uint* hout = hB;
    for (int l = 0; l < LAYERS; ++l) {
        k_spmm<<<(N_NODES + 7) / 8, 256, 0, stream>>>(hin, h0, dinv, indptr,
                                                      csr, hout);
        float beta = logf(THETA / (float)(l + 1) + 1.0f);
        k_gemm_layer<<<gemm_blocks, 256, 0, stream>>>(
            hout, Wt + (size_t)l * HID * HID, hin, beta);
        // note: k_gemm_layer reads hout (s) and writes hin (next h) in place of
        // the old h -- safe because s fully replaces h before the next spmm.
    }
    k_out<<<(N_NODES + 3) / 4, 256, 0, stream>>>(hin, W_out, b_out, out);
}

// Round 4
// 1298.015 us; speedup vs baseline: 1.3629x; 1.0419x over previous
//
#include <hip/hip_runtime.h>
#include <hip/hip_bf16.h>
#include <math.h>

// Problem constants (match reference)
#define N_NODES 100000
#define N_EDGES 3200000
#define HID 128
#define LAYERS 8
#define ALPHA 0.1f
#define THETA 0.5f

// Bucketed CSR build: 391 buckets x 256 dst nodes.
#define NBKT 391
#define BKT_STRIDE 10240
#define EPT 16
#define CHUNK 4096   // edges per block in k_bucket (256 thr x 16)

typedef unsigned int uint;
typedef unsigned short ushort;
typedef __attribute__((ext_vector_type(8))) short short8;   // 8 bf16 (4 VGPRs)
typedef __attribute__((ext_vector_type(4))) float f32x4;    // MFMA acc

// bf16 helpers: node features stored as packed bf16 pairs (uint = 2 cols)
__device__ inline float bf_lo(uint p) { return __uint_as_float(p << 16); }
__device__ inline float bf_hi(uint p) { return __uint_as_float(p & 0xffff0000u); }
__device__ inline uint bf_pack(float x, float y) {
    uint ux = __float_as_uint(x), uy = __float_as_uint(y);
    uint rx = (ux + 0x7fffu + ((ux >> 16) & 1u)) >> 16;
    uint ry = (uy + 0x7fffu + ((uy >> 16) & 1u)) >> 16;
    return rx | (ry << 16);
}
__device__ inline ushort bfr(float x) {
    uint u = __float_as_uint(x);
    return (ushort)((u + 0x7fffu + ((u >> 16) & 1u)) >> 16);
}
__device__ inline float bff(ushort s) { return __uint_as_float(((uint)s) << 16); }

// ---------------------------------------------------------------------------
// Pass A: chunk-wise counting sort of edges into 391 dst-buckets.
// ---------------------------------------------------------------------------
__global__ __launch_bounds__(256) void k_bucket(const int* __restrict__ rowi,
                                                const int* __restrict__ coli,
                                                uint* __restrict__ eb,
                                                int* __restrict__ gcnt) {
    __shared__ int bcnt[NBKT];
    __shared__ int gbase[NBKT];
    int t = threadIdx.x;
    for (int i = t; i < NBKT; i += 256) bcnt[i] = 0;
    __syncthreads();

    int e0 = blockIdx.x * CHUNK;
    int bk[EPT];
    int rk[EPT];
    uint rec[EPT];
#pragma unroll
    for (int j = 0; j < EPT; ++j) {
        int e = e0 + j * 256 + t;
        if (e < N_EDGES) {
            int r = rowi[e];
            int c = coli[e];
            bk[j] = c >> 8;
            rec[j] = ((uint)r << 8) | (uint)(c & 255);
            rk[j] = atomicAdd(&bcnt[bk[j]], 1);
        } else {
            bk[j] = -1;
        }
    }
    __syncthreads();
    for (int i = t; i < NBKT; i += 256) {
        int n = bcnt[i];
        gbase[i] = n ? atomicAdd(&gcnt[i], n) : 0;
    }
    __syncthreads();
#pragma unroll
    for (int j = 0; j < EPT; ++j) {
        if (bk[j] >= 0)
            eb[(size_t)bk[j] * BKT_STRIDE + gbase[bk[j]] + rk[j]] = rec[j];
    }
}

// Pass B: exclusive scan of the 391 bucket counts -> bucket bases in csr.
__global__ __launch_bounds__(512) void k_bscan(const int* __restrict__ gcnt,
                                               int* __restrict__ bbase) {
    __shared__ int lds[512];
    int t = threadIdx.x;
    int v = (t < NBKT) ? gcnt[t] : 0;
    lds[t] = v;
    __syncthreads();
    for (int off = 1; off < 512; off <<= 1) {
        int u = (t >= off) ? lds[t - off] : 0;
        __syncthreads();
        lds[t] += u;
        __syncthreads();
    }
    if (t < NBKT) bbase[t] = lds[t] - v;
}

// Pass C: per bucket, count edges per node in LDS, emit dinv + indptr.
__global__ __launch_bounds__(256) void k_node_ipt(const uint* __restrict__ eb,
                                                  const int* __restrict__ gcnt,
                                                  const int* __restrict__ bbase,
                                                  float* __restrict__ dinv,
                                                  int* __restrict__ indptr) {
    __shared__ int ncnt[256];
    __shared__ int sc[256];
    int b = blockIdx.x;
    int t = threadIdx.x;
    ncnt[t] = 0;
    __syncthreads();
    int ne = gcnt[b];
    const uint* ebp = eb + (size_t)b * BKT_STRIDE;
    for (int i = t; i < ne; i += 256) atomicAdd(&ncnt[ebp[i] & 255], 1);
    __syncthreads();
    int v = ncnt[t];
    sc[t] = v;
    __syncthreads();
    for (int off = 1; off < 256; off <<= 1) {
        int u = (t >= off) ? sc[t - off] : 0;
        __syncthreads();
        sc[t] += u;
        __syncthreads();
    }
    int node = b * 256 + t;
    if (node < N_NODES) {
        dinv[node] = rsqrtf((float)(v + 1));      // +1 self loop
        indptr[node] = bbase[b] + (sc[t] - v);
    }
    if (b == NBKT - 1 && t == 255) indptr[N_NODES] = N_EDGES;
}

// Pass D: per bucket, scatter src indices into per-node CSR segments.
// csr diet: 4 B/edge (src only). Weight dinv[r]*dinv[c] is reconstructed in
// the spmm as (sum dinv[r]*h[r]) * dinv[c]: dinv factoring moves dinv[c] out
// of the edge loop and dinv[r] becomes an L2-resident 400 KB broadcast gather.
__global__ __launch_bounds__(256) void k_fill2(const uint* __restrict__ eb,
                                               const int* __restrict__ gcnt,
                                               const int* __restrict__ indptr,
                                               int* __restrict__ csr) {
    __shared__ int scur[256];
    __shared__ int sipt[256];
    int b = blockIdx.x;
    int t = threadIdx.x;
    int node = b * 256 + t;
    sipt[t] = (node < N_NODES) ? indptr[node] : 0;
    scur[t] = 0;
    __syncthreads();
    int ne = gcnt[b];
    const uint* ebp = eb + (size_t)b * BKT_STRIDE;
    for (int i = t; i < ne; i += 256) {
        uint rec = ebp[i];
        int lc = rec & 255;
        int pos = sipt[lc] + atomicAdd(&scur[lc], 1);
        csr[pos] = (int)(rec >> 8);
    }
}

// ---------------------------------------------------------------------------
// W_gcn prep: bf16 + transpose -> Wt[l][c][k]  (runs once per call, 8 blocks)
// ---------------------------------------------------------------------------
__global__ __launch_bounds__(256) void k_wprep(const float* __restrict__ Wg,
                                               ushort* __restrict__ Wt) {
    int l = blockIdx.x;
    const float* W = Wg + (size_t)l * HID * HID;
    ushort* T = Wt + (size_t)l * HID * HID;
    int t = threadIdx.x;
#pragma unroll
    for (int i = 0; i < 16; ++i) {
        int idx = t + 256 * i;          // float4 id, 0..4095
        int k = idx >> 5;               // 0..127
        int c4 = idx & 31;
        float4 v = *(const float4*)(W + (size_t)k * HID + c4 * 4);
        T[(c4 * 4 + 0) * HID + k] = bfr(v.x);
        T[(c4 * 4 + 1) * HID + k] = bfr(v.y);
        T[(c4 * 4 + 2) * HID + k] = bfr(v.z);
        T[(c4 * 4 + 3) * HID + k] = bfr(v.w);
    }
}

// ---------------------------------------------------------------------------
// SpMM: s[n] = 0.9*dinv[n]*(sum_e dinv[src]*h[src] + dinv[n]*h[n]) + 0.1*h0[n]
// 32 lanes per node, 2 nodes per wave; lane holds 4 features (8B dwordx2
// gathers). csr entry = src index only; dinv[src] is a same-address broadcast
// load hitting the L2-resident 400 KB dinv table.
// Evidence (R1 vs R3): this kernel is bound at ~3.6 TB/s on the L2-miss path
// (identical FETCH+dur across 2x different VALU/MLP shapes) -> only byte
// reduction moves it.
// ---------------------------------------------------------------------------
__global__ __launch_bounds__(256) void k_spmm(const uint* __restrict__ h,
                                              const uint* __restrict__ h0,
                                              const float* __restrict__ dinv,
                                              const int* __restrict__ indptr,
                                              const int* __restrict__ csr,
                                              uint* __restrict__ s_out) {
    int node = blockIdx.x * 8 + (threadIdx.x >> 5);
    if (node >= N_NODES) return;
    int l = threadIdx.x & 31;
    int beg = indptr[node];
    int end = indptr[node + 1];
    // prefetch self/residual rows early (independent of edge loop)
    float di = dinv[node];
    uint2 hs = *(const uint2*)(h + node * 64 + l * 2);
    uint2 h0v = *(const uint2*)(h0 + node * 64 + l * 2);
    float a0[2] = {0.f, 0.f}, a1[2] = {0.f, 0.f};
    float a2[2] = {0.f, 0.f}, a3[2] = {0.f, 0.f};
    int e = beg;
    for (; e + 8 <= end; e += 8) {
        int sr[8];
#pragma unroll
        for (int j = 0; j < 8; ++j) sr[j] = csr[e + j];
        float dv[8];
#pragma unroll
        for (int j = 0; j < 8; ++j) dv[j] = dinv[sr[j]];
        uint2 p[8];
#pragma unroll
        for (int j = 0; j < 8; ++j) p[j] = *(const uint2*)(h + sr[j] * 64 + l * 2);
#pragma unroll
        for (int j = 0; j < 8; ++j) {
            float w = dv[j];
            int d = j & 1;
            a0[d] = fmaf(w, bf_lo(p[j].x), a0[d]);
            a1[d] = fmaf(w, bf_hi(p[j].x), a1[d]);
            a2[d] = fmaf(w, bf_lo(p[j].y), a2[d]);
            a3[d] = fmaf(w, bf_hi(p[j].y), a3[d]);
        }
    }
    for (; e < end; e += 2) {
        int sr[2];
        float w[2];
#pragma unroll
        for (int j = 0; j < 2; ++j) {
            int idx = e + j;
            sr[j] = csr[idx < end ? idx : beg];
            w[j] = (idx < end) ? dinv[sr[j]] : 0.f;
        }
        uint2 p[2];
#pragma unroll
        for (int j = 0; j < 2; ++j) p[j] = *(const uint2*)(h + sr[j] * 64 + l * 2);
#pragma unroll
        for (int j = 0; j < 2; ++j) {
            a0[j] = fmaf(w[j], bf_lo(p[j].x), a0[j]);
            a1[j] = fmaf(w[j], bf_hi(p[j].x), a1[j]);
            a2[j] = fmaf(w[j], bf_lo(p[j].y), a2[j]);
            a3[j] = fmaf(w[j], bf_hi(p[j].y), a3[j]);
        }
    }
    float s0 = a0[0] + a0[1];
    float s1 = a1[0] + a1[1];
    float s2 = a2[0] + a2[1];
    float s3 = a3[0] + a3[1];
    float sc = (1.0f - ALPHA) * di;
    float rx = sc * fmaf(di, bf_lo(hs.x), s0) + ALPHA * bf_lo(h0v.x);
    float ry = sc * fmaf(di, bf_hi(hs.x), s1) + ALPHA * bf_hi(h0v.x);
    float rz = sc * fmaf(di, bf_lo(hs.y), s2) + ALPHA * bf_lo(h0v.y);
    float rw = sc * fmaf(di, bf_hi(hs.y), s3) + ALPHA * bf_hi(h0v.y);
    uint2 o;
    o.x = bf_pack(rx, ry);
    o.y = bf_pack(rz, rw);
    *(uint2*)(s_out + node * 64 + l * 2) = o;
}

// ---------------------------------------------------------------------------
// GEMM initial projection: out0 = x@W_in + b_in  (fp32 in, bf16 out, single
// write -- layer-0 spmm reads this buffer as both h and h0)
// ---------------------------------------------------------------------------
__global__ __launch_bounds__(256) void k_gemm_in(const float* __restrict__ A,
                                                 const float* __restrict__ W,
                                                 const float* __restrict__ bias,
                                                 uint* __restrict__ out0) {
    __shared__ float sT[32 * 64];    // [k][r]
    __shared__ float Ws[32 * 128];   // [k][c]
    int t = threadIdx.x;
    int tr = t & 15;
    int tc = t >> 4;
    int rowBase = blockIdx.x * 64;
    float acc[4][8] = {};

    for (int ko = 0; ko < HID; ko += 32) {
#pragma unroll
        for (int pass = 0; pass < 2; ++pass) {
            int lin = t + 256 * pass;
            int r = lin >> 3;
            int kq = lin & 7;
            int ar = rowBase + r;
            if (ar >= N_NODES) ar = N_NODES - 1;
            float4 v = *(const float4*)(A + (size_t)ar * HID + ko + 4 * kq);
            sT[(4 * kq + 0) * 64 + r] = v.x;
            sT[(4 * kq + 1) * 64 + r] = v.y;
            sT[(4 * kq + 2) * 64 + r] = v.z;
            sT[(4 * kq + 3) * 64 + r] = v.w;
        }
#pragma unroll
        for (int pass = 0; pass < 4; ++pass) {
            int lin = t + 256 * pass;
            int k = lin >> 5;
            int c4 = lin & 31;
            *(float4*)&Ws[k * 128 + 4 * c4] =
                *(const float4*)(W + (size_t)(ko + k) * HID + 4 * c4);
        }
        __syncthreads();
#pragma unroll
        for (int k = 0; k < 32; ++k) {
            float4 a = *(const float4*)&sT[k * 64 + 4 * tr];
            float4 w0 = *(const float4*)&Ws[k * 128 + 8 * tc];
            float4 w1 = *(const float4*)&Ws[k * 128 + 8 * tc + 4];
            float av[4] = {a.x, a.y, a.z, a.w};
            float wv[8] = {w0.x, w0.y, w0.z, w0.w, w1.x, w1.y, w1.z, w1.w};
#pragma unroll
            for (int i = 0; i < 4; ++i)
#pragma unroll
                for (int j = 0; j < 8; ++j)
                    acc[i][j] = fmaf(av[i], wv[j], acc[i][j]);
        }
        __syncthreads();
    }

    int c0 = 8 * tc;
    float bb[8];
#pragma unroll
    for (int j = 0; j < 8; ++j) bb[j] = bias[c0 + j];
#pragma unroll
    for (int i = 0; i < 4; ++i) {
        int r = rowBase + 4 * tr + i;
        if (r >= N_NODES) break;
        float v[8];
#pragma unroll
        for (int j = 0; j < 8; ++j) v[j] = acc[i][j] + bb[j];
        uint4 o;
        o.x = bf_pack(v[0], v[1]);
        o.y = bf_pack(v[2], v[3]);
        o.z = bf_pack(v[4], v[5]);
        o.w = bf_pack(v[6], v[7]);
        *(uint4*)(out0 + (size_t)r * 64 + c0 / 2) = o;
    }
}

// ---------------------------------------------------------------------------
// GCNII layer GEMM (MFMA bf16): h' = relu((1-beta)*s + beta*(s@W))
// 64 rows x 128 cols per block, 4 waves; wave w owns cols [32w, 32w+32).
// B-fragments read directly from global Wt (32KB/layer, L2-hot broadcast).
// Last layer (Wo != nullptr): h' never hits HBM -- dot with W_out from the
// LDS pack buffer and write the scalar output (saves 51 MB round-trip + a
// dispatch).
// ---------------------------------------------------------------------------
#define SAS 136   // ushort stride (128+8): 272B rows, 16B-aligned, bank-even

__global__ __launch_bounds__(256) void k_gemm_layer(const uint* __restrict__ A,
                                                    const ushort* __restrict__ Wt,
                                                    uint* __restrict__ out0,
                                                    float beta,
                                                    const float* __restrict__ Wo,
                                                    const float* __restrict__ b_out,
                                                    float* __restrict__ outf) {
    __shared__ ushort sA[64 * SAS];
    __shared__ ushort pack[64 * 128];
    __shared__ float sWo[128];
    int t = threadIdx.x;
    int lane = t & 63;
    int wv = t >> 6;
    int rowBase = blockIdx.x * 64;

#pragma unroll
    for (int i = 0; i < 4; ++i) {
        int idx = t + 256 * i;          // 0..1023
        int r = idx >> 4;               // 0..63
        int q = idx & 15;               // uint4 within row
        int ar = rowBase + r;
        if (ar >= N_NODES) ar = N_NODES - 1;
        uint4 v = *(const uint4*)(A + (size_t)ar * 64 + q * 4);
        *(uint4*)((uint*)(sA + r * SAS) + q * 4) = v;
    }
    if (Wo != nullptr && t < 128) sWo[t] = Wo[t];
    __syncthreads();

    int fr = lane & 15;
    int fq = lane >> 4;
    const ushort* Wb0 = Wt + (size_t)(wv * 32 + fr) * HID;
    const ushort* Wb1 = Wt + (size_t)(wv * 32 + 16 + fr) * HID;
    f32x4 acc[4][2] = {};
#pragma unroll
    for (int kc = 0; kc < 4; ++kc) {
        int kof = kc * 32 + fq * 8;
        short8 b0 = *(const short8*)(Wb0 + kof);
        short8 b1 = *(const short8*)(Wb1 + kof);
#pragma unroll
        for (int tm = 0; tm < 4; ++tm) {
            short8 a = *(const short8*)(sA + (tm * 16 + fr) * SAS + kof);
            acc[tm][0] = __builtin_amdgcn_mfma_f32_16x16x32_bf16(a, b0, acc[tm][0], 0, 0, 0);
            acc[tm][1] = __builtin_amdgcn_mfma_f32_16x16x32_bf16(a, b1, acc[tm][1], 0, 0, 0);
        }
    }

    float ob = 1.0f - beta;
#pragma unroll
    for (int tm = 0; tm < 4; ++tm)
#pragma unroll
        for (int tn = 0; tn < 2; ++tn)
#pragma unroll
            for (int r = 0; r < 4; ++r) {
                int row = tm * 16 + fq * 4 + r;
                int col = wv * 32 + tn * 16 + fr;
                float sv = bff(sA[row * SAS + col]);
                float val = fmaxf(fmaf(ob, sv, beta * acc[tm][tn][r]), 0.f);
                pack[row * 128 + col] = bfr(val);
            }
    __syncthreads();

    if (Wo == nullptr) {
#pragma unroll
        for (int i = 0; i < 4; ++i) {
            int idx = t + 256 * i;
            int r = idx >> 4;
            int q = idx & 15;
            int ar = rowBase + r;
            if (ar < N_NODES)
                *(uint4*)(out0 + (size_t)ar * 64 + q * 4) =
                    *(const uint4*)((const uint*)(pack + r * 128) + q * 4);
        }
    } else {
        // final output: out[row] = dot(pack[row], W_out) + b_out
        int row = t >> 2;       // 0..63
        int sub = t & 3;        // 32-col slice per thread
        const ushort* pr_row = pack + row * 128 + sub * 32;
        float pr = 0.f;
#pragma unroll
        for (int i = 0; i < 32; i += 2) {
            uint pp = *(const uint*)(pr_row + i);
            pr = fmaf(bf_lo(pp), sWo[sub * 32 + i], pr);
            pr = fmaf(bf_hi(pp), sWo[sub * 32 + i + 1], pr);
        }
        pr += __shfl_xor(pr, 1);
        pr += __shfl_xor(pr, 2);
        int ar = rowBase + row;
        if (sub == 0 && ar < N_NODES) outf[ar] = pr + b_out[0];
    }
}

// ---------------------------------------------------------------------------
extern "C" void kernel_launch(void* const* d_in, const int* in_sizes, int n_in,
                              void* d_out, int out_size, void* d_ws, size_t ws_size,
                              hipStream_t stream) {
    const float* x     = (const float*)d_in[0];
    // d_in[1] edge_weight: unused by reference forward path
    const float* W_in  = (const float*)d_in[2];
    const float* b_in  = (const float*)d_in[3];
    const float* W_gcn = (const float*)d_in[4];
    const float* W_out = (const float*)d_in[5];
    const float* b_out = (const float*)d_in[6];
    const int*   ei    = (const int*)d_in[7];
    const int* rowi = ei;
    const int* coli = ei + N_EDGES;
    float* out = (float*)d_out;

    char* ws = (char*)d_ws;
    auto alloc = [&](size_t bytes) -> char* {
        char* p = ws;
        ws += (bytes + 255) & ~(size_t)255;
        return p;
    };
    float*  dinv    = (float*) alloc((size_t)N_NODES * 4);
    int*    indptr  = (int*)   alloc((size_t)(N_NODES + 1) * 4);
    int*    gcnt    = (int*)   alloc(2048 * 4);
    int*    bbase   = (int*)   alloc(2048 * 4);
    int*    csr     = (int*)   alloc((size_t)N_EDGES * 4);
    ushort* Wt      = (ushort*)alloc((size_t)LAYERS * HID * HID * 2);
    uint*   hA      = (uint*)  alloc((size_t)N_NODES * 64 * 4);  // bf16 x2 packed
    uint*   hB      = (uint*)  alloc((size_t)N_NODES * 64 * 4);
    uint*   h0      = (uint*)  alloc((size_t)N_NODES * 64 * 4);
    // bucket-sorted edge records (16.0 MB) alias hB: dead before first k_spmm
    uint*   eb      = hB;

    hipMemsetAsync(gcnt, 0, (size_t)NBKT * 4, stream);

    k_bucket<<<(N_EDGES + CHUNK - 1) / CHUNK, 256, 0, stream>>>(rowi, coli, eb, gcnt);
    k_bscan<<<1, 512, 0, stream>>>(gcnt, bbase);
    k_node_ipt<<<NBKT, 256, 0, stream>>>(eb, gcnt, bbase, dinv, indptr);
    k_fill2<<<NBKT, 256, 0, stream>>>(eb, gcnt, indptr, csr);
    k_wprep<<<LAYERS, 256, 0, stream>>>(W_gcn, Wt);

    int gemm_blocks = (N_NODES + 63) / 64;
    // h0 = x@W_in + b_in (single write; layer-0 spmm reads h0 as h too)
    k_gemm_in<<<gemm_blocks, 256, 0, stream>>>(x, W_in, b_in, h0);

    for (int l = 0; l < LAYERS; ++l) {
        const uint* hsrc = (l == 0) ? h0 : hA;
        k_spmm<<<(N_NODES + 7) / 8, 256, 0, stream>>>(hsrc, h0, dinv, indptr,
                                                      csr, hB);
        float beta = logf(THETA / (float)(l + 1) + 1.0f);
        bool last = (l == LAYERS - 1);
        k_gemm_layer<<<gemm_blocks, 256, 0, stream>>>(
            hB, Wt + (size_t)l * HID * HID, hA, beta,
            last ? W_out : nullptr, b_out, out);
    }
}